// Round 14
// baseline (202.689 us; speedup 1.0000x reference)
//
#include <hip/hip_runtime.h>
#include <math.h>

// Problem constants: B=8, C=64 (in), OC=64 (out), H=W=128, K=3x3=9, PAD=1.
#define Hn 128
#define Wn 128
#define HW 16384
#define NPIX 131072
#define EPSv 1e-5f

// ws layout (floats)
#define XT_OFF   0            // x_t bf16 channels-last [b][y][x][c]: 8388608 shorts = 4194304 floats
#define WBTA_OFF 4194304      // 20480 shorts = 10240 floats
#define WBTB_OFF 4204544      // 40960 shorts = 20480 floats
#define STAT_OFF 4225024      // 8 replicas x 128 (sum[64], sumsq[64]) = 1024 floats

// R24 (this round): async phase-1 staging. R23's staging round-trips
// global->VGPR->ds_write and serializes at the chunk barrier. The stage
// layout is already wave-uniform-base + lane*16B -> global_load_lds
// width=16 applies directly (Common-mistake #1 fix). T3 minimum 2-phase:
// issue STAGE(buf^1, chunk+1) BEFORE the MFMA section; __syncthreads'
// drain lands after ~500cy of MFMA has hidden the latency. OOB rows
// (h=0/127, block-uniform) zero-filled via ds_write. LDS union keeps
// 4 blocks/CU: stage dbuf (24.6KB, phase-1-only) aliases geow/geoi
// (11.5KB, phase-2+) -> total 38.4KB. Phases 2/3/epilogue byte-identical
// to R23 (passed, 201.4us). Counted-vmcnt asm gathers for phase 3 are
// permanently ruled out: wbtB B-fragment loads are compiler-scheduled
// global vmem -> hand vmcnt counts are unsound.

typedef short s16x8 __attribute__((ext_vector_type(8)));
typedef unsigned short u16x4 __attribute__((ext_vector_type(4)));
typedef float f32x4 __attribute__((ext_vector_type(4)));
typedef unsigned int u32x4 __attribute__((ext_vector_type(4)));

__device__ __forceinline__ unsigned short f2bf(float f) {
  unsigned u = __float_as_uint(f);
  return (unsigned short)((u + 0x7fffu + ((u >> 16) & 1u)) >> 16);  // RNE
}
__device__ __forceinline__ float bf2f(unsigned short s) {
  return __uint_as_float((unsigned)s << 16);
}
__device__ __forceinline__ unsigned cvt_pk_bf16(float lo, float hi) {
  unsigned r;
  asm("v_cvt_pk_bf16_f32 %0, %1, %2" : "=v"(r) : "v"(lo), "v"(hi));
  return r;
}

// ---------------- merged prep(+stat zero) + xform kernel ----------------
// blocks 0..511: xform x (NCHW fp32) -> x_t (NHWC bf16). blocks 512..751: weight pack.
__global__ __launch_bounds__(256) void prep_xform_kernel(
    const float* __restrict__ x, unsigned short* __restrict__ xt,
    const float* __restrict__ off_w, const float* __restrict__ mod_w,
    const float* __restrict__ w, unsigned short* __restrict__ wbtA,
    unsigned short* __restrict__ wbtB, float* __restrict__ stat) {
  int blk = blockIdx.x;
  if (blk < 512) {
    int b = blk & 7;
    int hw = ((blk >> 3) << 8) + threadIdx.x;   // 0..16383
    const float* xb = x + ((size_t)(b << 6) << 14) + hw;
    unsigned short* o = xt + (((size_t)(b << 14)) + hw) * 64;
#pragma unroll
    for (int g = 0; g < 8; ++g) {
      float v[8];
#pragma unroll
      for (int j = 0; j < 8; ++j) v[j] = xb[(size_t)((g << 3) + j) << 14];
      s16x8 pk;
#pragma unroll
      for (int j = 0; j < 8; ++j) pk[j] = (short)f2bf(v[j]);
      *(s16x8*)(o + (g << 3)) = pk;
    }
    return;
  }
  int i = ((blk - 512) << 8) + threadIdx.x;
  if (i < 1024) stat[i] = 0.f;   // 8 replica slots
  if (i < 20480) {
    // wbtA: A-operand (weights as rows) for phase 1 of the fused kernel.
    int e = i & 31, oc = (i >> 5) & 31, it = i >> 10;
    int tp = it % 5, chunk = it / 5;
    int tap = tp * 2 + (e >> 4);
    int c = (chunk << 4) + (e & 15);
    float v = 0.f;
    if (tap < 9) {
      if (oc < 18) v = off_w[(oc * 64 + c) * 9 + tap];
      else if (oc < 27) v = mod_w[((oc - 18) * 64 + c) * 9 + tap];
    }
    wbtA[i] = f2bf(v);
  } else if (i < 20480 + 40960) {
    // wbtB: B-operand fragments for phase 3 (deform).
    // index = ((it*4 + nt)*64 + lane)*8 + j
    // value = w[oc = nt*16 + (lane&15)][c][tap], where
    //   tap = (it%5)*2 + (lane>>5), c = (it/5)*16 + ((lane>>4)&1)*8 + j
    int j = i - 20480;
    int j3 = j & 7;
    int l = (j >> 3) & 63;
    int nt = (j >> 9) & 3;
    int it = j >> 11;
    int tp = it % 5, chunk = it / 5;
    int tap = tp * 2 + (l >> 5);
    int c = (chunk << 4) + (((l >> 4) & 1) << 3) + j3;
    int oc = (nt << 4) + (l & 15);
    float v = (tap < 9) ? w[(oc * 64 + c) * 9 + tap] : 0.f;
    wbtB[j] = f2bf(v);
  }
}

// ---------------- fused kernel: convA (async-staged ->LDS) + geometry + deform MFMA + stats ----------------
__global__ __launch_bounds__(256, 4) void fused_dconv_kernel(
    const unsigned short* __restrict__ xt, const unsigned short* __restrict__ wbtA,
    const unsigned short* __restrict__ wbtB,
    const float* __restrict__ off_b, const float* __restrict__ mod_b,
    const float* __restrict__ bias, float* __restrict__ y,
    float* __restrict__ stat) {
  __shared__ float offm[27 * 128];              // 13824 B; reused for stats reduce at the end
  // union: stage double-buffer (phase 1 only) aliases geow/geoi (phase 2+)
  __shared__ unsigned short un[2 * 3 * 128 * 16];  // 24576 B
  unsigned short* geow = un;                    // 9216 B: w00,w01,w10,w11 bf16 (mask folded)
  unsigned short* geoi = un + 4608;             // 2304 B: ibase = rbase*128+cbase
  int t = threadIdx.x;
  int bx = blockIdx.x;                  // 1024 = 8 b x 128 h
  int b = bx & 7, h = bx >> 3;
  int lane = t & 63, wv = t >> 6;
  int ln = lane & 15, quad = (lane >> 4) & 3;
  int hw = h << 7;

  const unsigned short* xtb = xt + ((size_t)(b << 14)) * 64;

  // ===== phase 1: offset+mask conv via MFMA (async global_load_lds staging, dbuf) =====
  {
    int p0 = (wv << 5) + ln, p1 = p0 + 16;
    int s_ = quad >> 1, cj = (quad & 1) << 3;
    int px_s = t >> 1, half_s = t & 1;   // staging lane mapping

    // STAGE(buf, chunk): issue 3-row async loads (row k OOB -> ds_write zeros)
    auto STAGE = [&](int buf, int chunk) {
#pragma unroll
      for (int k = 0; k < 3; ++k) {
        int gy = h - 1 + k;
        unsigned short* lp = un + buf * 6144 + (k << 11) + (wv << 9);  // wave-uniform base
        if ((unsigned)gy < 128u) {
          const unsigned short* gp =
              xtb + ((size_t)gy << 13) + (px_s << 6) + (chunk << 4) + (half_s << 3);
          __builtin_amdgcn_global_load_lds(
              (const __attribute__((address_space(1))) unsigned int*)gp,
              (__attribute__((address_space(3))) unsigned int*)lp, 16, 0, 0);
        } else {
          *(s16x8*)(un + buf * 6144 + (k << 11) + (t << 3)) = (s16x8){0, 0, 0, 0, 0, 0, 0, 0};
        }
      }
    };

    f32x4 acc1[2][2];
#pragma unroll
    for (int mt = 0; mt < 2; ++mt)
#pragma unroll
      for (int nt = 0; nt < 2; ++nt) acc1[mt][nt] = (f32x4){0.f, 0.f, 0.f, 0.f};

    STAGE(0, 0);
    __syncthreads();   // drain prologue loads

    for (int chunk = 0; chunk < 4; ++chunk) {
      if (chunk < 3) STAGE((chunk + 1) & 1, chunk + 1);  // async prefetch, flies under MFMAs
      const unsigned short* sb = un + (chunk & 1) * 6144;
#pragma unroll
      for (int tp = 0; tp < 5; ++tp) {
        int it = chunk * 5 + tp;
        int tap = tp * 2 + s_;
        s16x8 B0 = (s16x8){0, 0, 0, 0, 0, 0, 0, 0};
        s16x8 B1 = (s16x8){0, 0, 0, 0, 0, 0, 0, 0};
        if (tap < 9) {
          const unsigned short* rowl = sb + (tap / 3) * 2048 + cj;
          int gx0 = p0 + tap % 3 - 1;
          int gx1 = p1 + tap % 3 - 1;
          if (gx0 >= 0 && gx0 < Wn) B0 = *(const s16x8*)(rowl + (gx0 << 4));
          if (gx1 >= 0 && gx1 < Wn) B1 = *(const s16x8*)(rowl + (gx1 << 4));
        }
#pragma unroll
        for (int mt = 0; mt < 2; ++mt) {
          s16x8 A = *(const s16x8*)(wbtA + (size_t)((it << 5) + (mt << 4) + ln) * 32 + (quad << 3));
          acc1[mt][0] = __builtin_amdgcn_mfma_f32_16x16x32_bf16(A, B0, acc1[mt][0], 0, 0, 0);
          acc1[mt][1] = __builtin_amdgcn_mfma_f32_16x16x32_bf16(A, B1, acc1[mt][1], 0, 0, 0);
        }
      }
      __syncthreads();   // drains prefetch (mostly complete under MFMAs) + protects dbuf
    }

#pragma unroll
    for (int mt = 0; mt < 2; ++mt)
#pragma unroll
      for (int r = 0; r < 4; ++r) {
        int oc = (mt << 4) + (quad << 2) + r;
#pragma unroll
        for (int nt = 0; nt < 2; ++nt) {
          int px = (wv << 5) + (nt << 4) + ln;
          float val = acc1[mt][nt][r];
          if (oc < 18) {
            offm[(oc << 7) + px] = val + off_b[oc];
          } else if (oc < 27) {
            float z = val + mod_b[oc - 18];
            offm[(oc << 7) + px] = 2.f / (1.f + expf(-z));
          }
        }
      }
  }
  __syncthreads();   // offm ready; stage buffers dead from here -> geow/geoi may alias

  // ===== phase 2: geometry for 128 px x 9 taps from LDS =====
  for (int i = t; i < 1152; i += 256) {
    int tap = i >> 7, p2 = i & 127;
    float dy = offm[((2 * tap) << 7) + p2];
    float dx = offm[((2 * tap + 1) << 7) + p2];
    float m = offm[((18 + tap) << 7) + p2];
    float py = dy + (float)(h + tap / 3 - 1);
    float pxf = dx + (float)(p2 + tap % 3 - 1);
    float y0f = floorf(py), x0f = floorf(pxf);
    float ly = py - y0f, lx = pxf - x0f;
    int y0 = (int)y0f, x0 = (int)x0f;
    int y1 = y0 + 1, x1 = x0 + 1;
    float fy0 = (y0 >= 0 && y0 < Hn) ? 1.f : 0.f;
    float fy1 = (y1 >= 0 && y1 < Hn) ? 1.f : 0.f;
    float fx0 = (x0 >= 0 && x0 < Wn) ? 1.f : 0.f;
    float fx1 = (x1 >= 0 && x1 < Wn) ? 1.f : 0.f;
    float ax0 = (1.f - lx) * fx0, ax1 = lx * fx1;
    float ay0 = (1.f - ly) * fy0 * m, ay1 = ly * fy1 * m;
    int cy0 = min(max(y0, 0), Hn - 1), cy1 = min(max(y1, 0), Hn - 1);
    int cx0 = min(max(x0, 0), Wn - 1), cx1 = min(max(x1, 0), Wn - 1);
    int cbase = min(cx0, Wn - 2), rbase = min(cy0, Hn - 2);
    float gx0 = (cx0 == cbase ? ax0 : 0.f) + (cx1 == cbase ? ax1 : 0.f);
    float gx1 = (cx0 == cbase + 1 ? ax0 : 0.f) + (cx1 == cbase + 1 ? ax1 : 0.f);
    float gy0 = (cy0 == rbase ? ay0 : 0.f) + (cy1 == rbase ? ay1 : 0.f);
    float gy1 = (cy0 == rbase + 1 ? ay0 : 0.f) + (cy1 == rbase + 1 ? ay1 : 0.f);
    unsigned short* gw = geow + i * 4;
    gw[0] = f2bf(gy0 * gx0);
    gw[1] = f2bf(gy0 * gx1);
    gw[2] = f2bf(gy1 * gx0);
    gw[3] = f2bf(gy1 * gx1);
    geoi[i] = (unsigned short)((rbase << 7) + cbase);
  }
  __syncthreads();

  // ===== phase 3: deform MFMA (R16 structure) + setprio around MFMA cluster =====
  int l4 = ln;
  int s4 = lane >> 4;        // k-slice 0..3
  int tapS = lane >> 5;      // which tap of the pair
  int chalf = s4 & 1;        // which 8ch half of the 16ch chunk

  f32x4 acc[2][4];  // [m-tile (px 16)][n-tile (oc 16)]
#pragma unroll
  for (int m = 0; m < 2; ++m)
#pragma unroll
    for (int n = 0; n < 4; ++n) acc[m][n] = (f32x4){0.f, 0.f, 0.f, 0.f};

  for (int tp = 0; tp < 5; ++tp) {
    int tap = tp * 2 + tapS;
    bool live = (tap < 9);
    float w00[2], w01[2], w10[2], w11[2];
    const unsigned short* cpb[2];
#pragma unroll
    for (int m = 0; m < 2; ++m) {
      if (live) {
        int px = (wv << 5) + (m << 4) + l4;
        int gidx = (tap << 7) + px;
        u16x4 wq = *(const u16x4*)(geow + gidx * 4);
        unsigned ib = geoi[gidx];
        w00[m] = bf2f(wq[0]);
        w01[m] = bf2f(wq[1]);
        w10[m] = bf2f(wq[2]);
        w11[m] = bf2f(wq[3]);
        cpb[m] = xtb + (size_t)ib * 64 + (chalf << 3);
      } else {
        cpb[m] = xtb;
        w00[m] = w01[m] = w10[m] = w11[m] = 0.f;
      }
    }
#pragma unroll 2
    for (int chunk = 0; chunk < 4; ++chunk) {
      int it = chunk * 5 + tp;
      s16x8 A[2];
#pragma unroll
      for (int m = 0; m < 2; ++m) {
        if (live) {
          const unsigned short* cp = cpb[m] + (chunk << 4);
          s16x8 c00 = *(const s16x8*)(cp);
          s16x8 c01 = *(const s16x8*)(cp + 64);
          s16x8 c10 = *(const s16x8*)(cp + 8192);
          s16x8 c11 = *(const s16x8*)(cp + 8192 + 64);
          u32x4 au;
#pragma unroll
          for (int jj = 0; jj < 4; ++jj) {
            float v0 = w00[m] * bf2f((unsigned short)c00[2 * jj]) +
                       w01[m] * bf2f((unsigned short)c01[2 * jj]) +
                       w10[m] * bf2f((unsigned short)c10[2 * jj]) +
                       w11[m] * bf2f((unsigned short)c11[2 * jj]);
            float v1 = w00[m] * bf2f((unsigned short)c00[2 * jj + 1]) +
                       w01[m] * bf2f((unsigned short)c01[2 * jj + 1]) +
                       w10[m] * bf2f((unsigned short)c10[2 * jj + 1]) +
                       w11[m] * bf2f((unsigned short)c11[2 * jj + 1]);
            au[jj] = cvt_pk_bf16(v0, v1);
          }
          A[m] = __builtin_bit_cast(s16x8, au);
        } else {
          A[m] = (s16x8){0, 0, 0, 0, 0, 0, 0, 0};
        }
      }
      const unsigned short* wb = wbtB + (((size_t)it) << 11) + (lane << 3);
      __builtin_amdgcn_s_setprio(1);
#pragma unroll
      for (int n = 0; n < 4; ++n) {
        s16x8 Bf = *(const s16x8*)(wb + (n << 9));
        acc[0][n] = __builtin_amdgcn_mfma_f32_16x16x32_bf16(A[0], Bf, acc[0][n], 0, 0, 0);
        acc[1][n] = __builtin_amdgcn_mfma_f32_16x16x32_bf16(A[1], Bf, acc[1][n], 0, 0, 0);
      }
      __builtin_amdgcn_s_setprio(0);
    }
  }

  // ===== epilogue: bias + store + per-channel stats (8-way replicated atomics) =====
  float sac[4], ssc[4];
#pragma unroll
  for (int n = 0; n < 4; ++n) { sac[n] = 0.f; ssc[n] = 0.f; }
#pragma unroll
  for (int m = 0; m < 2; ++m) {
    int px0 = (wv << 5) + (m << 4) + (s4 << 2);
#pragma unroll
    for (int n = 0; n < 4; ++n) {
      int oc = (n << 4) + l4;
      float bv = bias[oc];
      float4 o;
      o.x = acc[m][n][0] + bv;
      o.y = acc[m][n][1] + bv;
      o.z = acc[m][n][2] + bv;
      o.w = acc[m][n][3] + bv;
      sac[n] += o.x + o.y + o.z + o.w;
      ssc[n] += o.x * o.x + o.y * o.y + o.z * o.z + o.w * o.w;
      *(float4*)(y + (((size_t)(b << 6) + oc) << 14) + hw + px0) = o;
    }
  }
  // reduce over the 4 k-slice lanes (same l4, different s4): xor 16, 32
#pragma unroll
  for (int n = 0; n < 4; ++n) {
    sac[n] += __shfl_xor(sac[n], 16);
    sac[n] += __shfl_xor(sac[n], 32);
    ssc[n] += __shfl_xor(ssc[n], 16);
    ssc[n] += __shfl_xor(ssc[n], 32);
  }
  if (lane < 16) {
#pragma unroll
    for (int n = 0; n < 4; ++n) {
      int oc = (n << 4) + lane;
      offm[(wv << 6) + oc] = sac[n];
      offm[256 + (wv << 6) + oc] = ssc[n];
    }
  }
  __syncthreads();
  if (t < 64) {
    float S = offm[t] + offm[64 + t] + offm[128 + t] + offm[192 + t];
    float SS = offm[256 + t] + offm[320 + t] + offm[384 + t] + offm[448 + t];
    float* sb = stat + ((bx & 7) << 7);   // replica slot: contention 1024 -> 128 per address
    atomicAdd(sb + t, S);
    atomicAdd(sb + 64 + t, SS);
  }
}

// ---------------- kernel D: batchnorm scale/shift + relu, in place ----------------
__global__ __launch_bounds__(256) void bnrelu_kernel(
    float* __restrict__ y, const float* __restrict__ stat,
    const float* __restrict__ gamma, const float* __restrict__ beta) {
  __shared__ float gs[64], bs[64];
  int t = threadIdx.x;
  if (t < 64) {
    float S = 0.f, SS = 0.f;
#pragma unroll
    for (int k = 0; k < 8; ++k) {
      S += stat[(k << 7) + t];
      SS += stat[(k << 7) + 64 + t];
    }
    float mean = S * (1.f / (float)NPIX);
    float var = SS * (1.f / (float)NPIX) - mean * mean;
    float r = rsqrtf(var + EPSv);
    float g = gamma[t] * r;
    gs[t] = g;
    bs[t] = beta[t] - mean * g;
  }
  __syncthreads();
  float4* y4 = (float4*)y;
  for (int i = blockIdx.x * 256 + t; i < 2097152; i += gridDim.x * 256) {
    int c = (i >> 12) & 63;
    float g = gs[c];
    float bt = bs[c];
    float4 v = y4[i];
    v.x = fmaxf(v.x * g + bt, 0.f);
    v.y = fmaxf(v.y * g + bt, 0.f);
    v.z = fmaxf(v.z * g + bt, 0.f);
    v.w = fmaxf(v.w * g + bt, 0.f);
    y4[i] = v;
  }
}

extern "C" void kernel_launch(void* const* d_in, const int* in_sizes, int n_in,
                              void* d_out, int out_size, void* d_ws, size_t ws_size,
                              hipStream_t stream) {
  const float* x     = (const float*)d_in[0];
  const float* off_w = (const float*)d_in[1];
  const float* off_b = (const float*)d_in[2];
  const float* mod_w = (const float*)d_in[3];
  const float* mod_b = (const float*)d_in[4];
  const float* w     = (const float*)d_in[5];
  const float* b     = (const float*)d_in[6];
  const float* gamma = (const float*)d_in[7];
  const float* beta  = (const float*)d_in[8];
  float* out = (float*)d_out;
  float* ws  = (float*)d_ws;

  unsigned short* xt  = (unsigned short*)(ws + XT_OFF);
  unsigned short* wbtA = (unsigned short*)(ws + WBTA_OFF);
  unsigned short* wbtB = (unsigned short*)(ws + WBTB_OFF);
  float* stat  = ws + STAT_OFF;

  prep_xform_kernel<<<752, 256, 0, stream>>>(x, xt, off_w, mod_w, w, wbtA, wbtB, stat);
  fused_dconv_kernel<<<1024, 256, 0, stream>>>(xt, wbtA, wbtB, off_b, mod_b, b, out, stat);
  bnrelu_kernel<<<2048, 256, 0, stream>>>(out, stat, gamma, beta);
}

// Round 15
// 202.371 us; speedup vs baseline: 1.0016x; 1.0016x over previous
//
#include <hip/hip_runtime.h>
#include <math.h>

// Problem constants: B=8, C=64 (in), OC=64 (out), H=W=128, K=3x3=9, PAD=1.
#define Hn 128
#define Wn 128
#define HW 16384
#define NPIX 131072
#define EPSv 1e-5f

// ws layout (floats)
#define XT_OFF   0            // x_t bf16 channels-last [b][y][x][c]: 8388608 shorts = 4194304 floats
#define WBTA_OFF 4194304      // 20480 shorts = 10240 floats
#define WBTB_OFF 4204544      // 40960 shorts = 20480 floats
#define STAT_OFF 4225024      // 8 replicas x 128 (sum[64], sumsq[64]) = 1024 floats

// R25 (this round): interp via v_dot2_f32_bf16. R24's async staging was
// null -> phase-1 exhausted. Remaining on-chain cost: phase-3 interp VALU
// (~2720 ops/thread: 4 bf2f + 4 FMA per element). Replace with bf16-pair
// dot products: per element v = dot2(wA,(c00,c01), dot2(wB,(c10,c11),0)).
// Weights stay packed bf16 (geow already stores bf16 pairs: wA=w00|w01<<16,
// wB=w10|w11<<16); corner pairs formed by one v_perm_b32 each
// (sel 0x01000504 / 0x03020706 for even/odd elements). Per (m,chunk):
// 68 -> 36 VALU ops; interp total 2720 -> ~1480/thread. Everything else
// byte-identical to R24 (passed, fused 102.7us). LDS-gather restructure
// for phase 3 REJECTED on arithmetic: 8-way-conflicted ds_read (write side
// is gload_lds-linear, can't swizzle both sides) costs more than the
// L1/L2-absorbed global gathers (FETCH only 8.8MB).

typedef short s16x8 __attribute__((ext_vector_type(8)));
typedef unsigned short u16x4 __attribute__((ext_vector_type(4)));
typedef float f32x4 __attribute__((ext_vector_type(4)));
typedef unsigned int u32x4 __attribute__((ext_vector_type(4)));

__device__ __forceinline__ unsigned short f2bf(float f) {
  unsigned u = __float_as_uint(f);
  return (unsigned short)((u + 0x7fffu + ((u >> 16) & 1u)) >> 16);  // RNE
}
__device__ __forceinline__ float bf2f(unsigned short s) {
  return __uint_as_float((unsigned)s << 16);
}
__device__ __forceinline__ unsigned cvt_pk_bf16(float lo, float hi) {
  unsigned r;
  asm("v_cvt_pk_bf16_f32 %0, %1, %2" : "=v"(r) : "v"(lo), "v"(hi));
  return r;
}
__device__ __forceinline__ float dot2bf(unsigned a, unsigned b, float c) {
  float d;
  asm("v_dot2_f32_bf16 %0, %1, %2, %3" : "=v"(d) : "v"(a), "v"(b), "v"(c));
  return d;
}

// ---------------- merged prep(+stat zero) + xform kernel ----------------
// blocks 0..511: xform x (NCHW fp32) -> x_t (NHWC bf16). blocks 512..751: weight pack.
__global__ __launch_bounds__(256) void prep_xform_kernel(
    const float* __restrict__ x, unsigned short* __restrict__ xt,
    const float* __restrict__ off_w, const float* __restrict__ mod_w,
    const float* __restrict__ w, unsigned short* __restrict__ wbtA,
    unsigned short* __restrict__ wbtB, float* __restrict__ stat) {
  int blk = blockIdx.x;
  if (blk < 512) {
    int b = blk & 7;
    int hw = ((blk >> 3) << 8) + threadIdx.x;   // 0..16383
    const float* xb = x + ((size_t)(b << 6) << 14) + hw;
    unsigned short* o = xt + (((size_t)(b << 14)) + hw) * 64;
#pragma unroll
    for (int g = 0; g < 8; ++g) {
      float v[8];
#pragma unroll
      for (int j = 0; j < 8; ++j) v[j] = xb[(size_t)((g << 3) + j) << 14];
      s16x8 pk;
#pragma unroll
      for (int j = 0; j < 8; ++j) pk[j] = (short)f2bf(v[j]);
      *(s16x8*)(o + (g << 3)) = pk;
    }
    return;
  }
  int i = ((blk - 512) << 8) + threadIdx.x;
  if (i < 1024) stat[i] = 0.f;   // 8 replica slots
  if (i < 20480) {
    // wbtA: A-operand (weights as rows) for phase 1 of the fused kernel.
    int e = i & 31, oc = (i >> 5) & 31, it = i >> 10;
    int tp = it % 5, chunk = it / 5;
    int tap = tp * 2 + (e >> 4);
    int c = (chunk << 4) + (e & 15);
    float v = 0.f;
    if (tap < 9) {
      if (oc < 18) v = off_w[(oc * 64 + c) * 9 + tap];
      else if (oc < 27) v = mod_w[((oc - 18) * 64 + c) * 9 + tap];
    }
    wbtA[i] = f2bf(v);
  } else if (i < 20480 + 40960) {
    // wbtB: B-operand fragments for phase 3 (deform).
    // index = ((it*4 + nt)*64 + lane)*8 + j
    // value = w[oc = nt*16 + (lane&15)][c][tap], where
    //   tap = (it%5)*2 + (lane>>5), c = (it/5)*16 + ((lane>>4)&1)*8 + j
    int j = i - 20480;
    int j3 = j & 7;
    int l = (j >> 3) & 63;
    int nt = (j >> 9) & 3;
    int it = j >> 11;
    int tp = it % 5, chunk = it / 5;
    int tap = tp * 2 + (l >> 5);
    int c = (chunk << 4) + (((l >> 4) & 1) << 3) + j3;
    int oc = (nt << 4) + (l & 15);
    float v = (tap < 9) ? w[(oc * 64 + c) * 9 + tap] : 0.f;
    wbtB[j] = f2bf(v);
  }
}

// ---------------- fused kernel: convA (async-staged ->LDS) + geometry + deform MFMA + stats ----------------
__global__ __launch_bounds__(256, 4) void fused_dconv_kernel(
    const unsigned short* __restrict__ xt, const unsigned short* __restrict__ wbtA,
    const unsigned short* __restrict__ wbtB,
    const float* __restrict__ off_b, const float* __restrict__ mod_b,
    const float* __restrict__ bias, float* __restrict__ y,
    float* __restrict__ stat) {
  __shared__ float offm[27 * 128];              // 13824 B; reused for stats reduce at the end
  // union: stage double-buffer (phase 1 only) aliases geow/geoi (phase 2+)
  __shared__ unsigned short un[2 * 3 * 128 * 16];  // 24576 B
  unsigned short* geow = un;                    // 9216 B: w00,w01,w10,w11 bf16 (mask folded)
  unsigned short* geoi = un + 4608;             // 2304 B: ibase = rbase*128+cbase
  int t = threadIdx.x;
  int bx = blockIdx.x;                  // 1024 = 8 b x 128 h
  int b = bx & 7, h = bx >> 3;
  int lane = t & 63, wv = t >> 6;
  int ln = lane & 15, quad = (lane >> 4) & 3;
  int hw = h << 7;

  const unsigned short* xtb = xt + ((size_t)(b << 14)) * 64;

  // ===== phase 1: offset+mask conv via MFMA (async global_load_lds staging, dbuf) =====
  {
    int p0 = (wv << 5) + ln, p1 = p0 + 16;
    int s_ = quad >> 1, cj = (quad & 1) << 3;
    int px_s = t >> 1, half_s = t & 1;   // staging lane mapping

    // STAGE(buf, chunk): issue 3-row async loads (row k OOB -> ds_write zeros)
    auto STAGE = [&](int buf, int chunk) {
#pragma unroll
      for (int k = 0; k < 3; ++k) {
        int gy = h - 1 + k;
        unsigned short* lp = un + buf * 6144 + (k << 11) + (wv << 9);  // wave-uniform base
        if ((unsigned)gy < 128u) {
          const unsigned short* gp =
              xtb + ((size_t)gy << 13) + (px_s << 6) + (chunk << 4) + (half_s << 3);
          __builtin_amdgcn_global_load_lds(
              (const __attribute__((address_space(1))) unsigned int*)gp,
              (__attribute__((address_space(3))) unsigned int*)lp, 16, 0, 0);
        } else {
          *(s16x8*)(un + buf * 6144 + (k << 11) + (t << 3)) = (s16x8){0, 0, 0, 0, 0, 0, 0, 0};
        }
      }
    };

    f32x4 acc1[2][2];
#pragma unroll
    for (int mt = 0; mt < 2; ++mt)
#pragma unroll
      for (int nt = 0; nt < 2; ++nt) acc1[mt][nt] = (f32x4){0.f, 0.f, 0.f, 0.f};

    STAGE(0, 0);
    __syncthreads();   // drain prologue loads

    for (int chunk = 0; chunk < 4; ++chunk) {
      if (chunk < 3) STAGE((chunk + 1) & 1, chunk + 1);  // async prefetch, flies under MFMAs
      const unsigned short* sb = un + (chunk & 1) * 6144;
#pragma unroll
      for (int tp = 0; tp < 5; ++tp) {
        int it = chunk * 5 + tp;
        int tap = tp * 2 + s_;
        s16x8 B0 = (s16x8){0, 0, 0, 0, 0, 0, 0, 0};
        s16x8 B1 = (s16x8){0, 0, 0, 0, 0, 0, 0, 0};
        if (tap < 9) {
          const unsigned short* rowl = sb + (tap / 3) * 2048 + cj;
          int gx0 = p0 + tap % 3 - 1;
          int gx1 = p1 + tap % 3 - 1;
          if (gx0 >= 0 && gx0 < Wn) B0 = *(const s16x8*)(rowl + (gx0 << 4));
          if (gx1 >= 0 && gx1 < Wn) B1 = *(const s16x8*)(rowl + (gx1 << 4));
        }
#pragma unroll
        for (int mt = 0; mt < 2; ++mt) {
          s16x8 A = *(const s16x8*)(wbtA + (size_t)((it << 5) + (mt << 4) + ln) * 32 + (quad << 3));
          acc1[mt][0] = __builtin_amdgcn_mfma_f32_16x16x32_bf16(A, B0, acc1[mt][0], 0, 0, 0);
          acc1[mt][1] = __builtin_amdgcn_mfma_f32_16x16x32_bf16(A, B1, acc1[mt][1], 0, 0, 0);
        }
      }
      __syncthreads();   // drains prefetch (mostly complete under MFMAs) + protects dbuf
    }

#pragma unroll
    for (int mt = 0; mt < 2; ++mt)
#pragma unroll
      for (int r = 0; r < 4; ++r) {
        int oc = (mt << 4) + (quad << 2) + r;
#pragma unroll
        for (int nt = 0; nt < 2; ++nt) {
          int px = (wv << 5) + (nt << 4) + ln;
          float val = acc1[mt][nt][r];
          if (oc < 18) {
            offm[(oc << 7) + px] = val + off_b[oc];
          } else if (oc < 27) {
            float z = val + mod_b[oc - 18];
            offm[(oc << 7) + px] = 2.f / (1.f + expf(-z));
          }
        }
      }
  }
  __syncthreads();   // offm ready; stage buffers dead from here -> geow/geoi may alias

  // ===== phase 2: geometry for 128 px x 9 taps from LDS =====
  for (int i = t; i < 1152; i += 256) {
    int tap = i >> 7, p2 = i & 127;
    float dy = offm[((2 * tap) << 7) + p2];
    float dx = offm[((2 * tap + 1) << 7) + p2];
    float m = offm[((18 + tap) << 7) + p2];
    float py = dy + (float)(h + tap / 3 - 1);
    float pxf = dx + (float)(p2 + tap % 3 - 1);
    float y0f = floorf(py), x0f = floorf(pxf);
    float ly = py - y0f, lx = pxf - x0f;
    int y0 = (int)y0f, x0 = (int)x0f;
    int y1 = y0 + 1, x1 = x0 + 1;
    float fy0 = (y0 >= 0 && y0 < Hn) ? 1.f : 0.f;
    float fy1 = (y1 >= 0 && y1 < Hn) ? 1.f : 0.f;
    float fx0 = (x0 >= 0 && x0 < Wn) ? 1.f : 0.f;
    float fx1 = (x1 >= 0 && x1 < Wn) ? 1.f : 0.f;
    float ax0 = (1.f - lx) * fx0, ax1 = lx * fx1;
    float ay0 = (1.f - ly) * fy0 * m, ay1 = ly * fy1 * m;
    int cy0 = min(max(y0, 0), Hn - 1), cy1 = min(max(y1, 0), Hn - 1);
    int cx0 = min(max(x0, 0), Wn - 1), cx1 = min(max(x1, 0), Wn - 1);
    int cbase = min(cx0, Wn - 2), rbase = min(cy0, Hn - 2);
    float gx0 = (cx0 == cbase ? ax0 : 0.f) + (cx1 == cbase ? ax1 : 0.f);
    float gx1 = (cx0 == cbase + 1 ? ax0 : 0.f) + (cx1 == cbase + 1 ? ax1 : 0.f);
    float gy0 = (cy0 == rbase ? ay0 : 0.f) + (cy1 == rbase ? ay1 : 0.f);
    float gy1 = (cy0 == rbase + 1 ? ay0 : 0.f) + (cy1 == rbase + 1 ? ay1 : 0.f);
    unsigned short* gw = geow + i * 4;
    gw[0] = f2bf(gy0 * gx0);
    gw[1] = f2bf(gy0 * gx1);
    gw[2] = f2bf(gy1 * gx0);
    gw[3] = f2bf(gy1 * gx1);
    geoi[i] = (unsigned short)((rbase << 7) + cbase);
  }
  __syncthreads();

  // ===== phase 3: deform MFMA; interp via v_perm + v_dot2_f32_bf16 =====
  int l4 = ln;
  int s4 = lane >> 4;        // k-slice 0..3
  int tapS = lane >> 5;      // which tap of the pair
  int chalf = s4 & 1;        // which 8ch half of the 16ch chunk

  f32x4 acc[2][4];  // [m-tile (px 16)][n-tile (oc 16)]
#pragma unroll
  for (int m = 0; m < 2; ++m)
#pragma unroll
    for (int n = 0; n < 4; ++n) acc[m][n] = (f32x4){0.f, 0.f, 0.f, 0.f};

  for (int tp = 0; tp < 5; ++tp) {
    int tap = tp * 2 + tapS;
    bool live = (tap < 9);
    unsigned wA[2], wB[2];   // packed bf16 pairs: wA=(w00,w01), wB=(w10,w11)
    const unsigned short* cpb[2];
#pragma unroll
    for (int m = 0; m < 2; ++m) {
      if (live) {
        int px = (wv << 5) + (m << 4) + l4;
        int gidx = (tap << 7) + px;
        u16x4 wq = *(const u16x4*)(geow + gidx * 4);
        unsigned ib = geoi[gidx];
        wA[m] = (unsigned)wq[0] | ((unsigned)wq[1] << 16);
        wB[m] = (unsigned)wq[2] | ((unsigned)wq[3] << 16);
        cpb[m] = xtb + (size_t)ib * 64 + (chalf << 3);
      } else {
        cpb[m] = xtb;
        wA[m] = 0u;
        wB[m] = 0u;
      }
    }
#pragma unroll 2
    for (int chunk = 0; chunk < 4; ++chunk) {
      int it = chunk * 5 + tp;
      s16x8 A[2];
#pragma unroll
      for (int m = 0; m < 2; ++m) {
        if (live) {
          const unsigned short* cp = cpb[m] + (chunk << 4);
          u32x4 a00 = *(const u32x4*)(cp);
          u32x4 a01 = *(const u32x4*)(cp + 64);
          u32x4 a10 = *(const u32x4*)(cp + 8192);
          u32x4 a11 = *(const u32x4*)(cp + 8192 + 64);
          u32x4 au;
#pragma unroll
          for (int d = 0; d < 4; ++d) {
            // even element of dword d: sel 0x01000504; odd: 0x03020706
            unsigned cA0 = __builtin_amdgcn_perm(a00[d], a01[d], 0x01000504u);
            unsigned cB0 = __builtin_amdgcn_perm(a10[d], a11[d], 0x01000504u);
            unsigned cA1 = __builtin_amdgcn_perm(a00[d], a01[d], 0x03020706u);
            unsigned cB1 = __builtin_amdgcn_perm(a10[d], a11[d], 0x03020706u);
            float v0 = dot2bf(wB[m], cB0, dot2bf(wA[m], cA0, 0.f));
            float v1 = dot2bf(wB[m], cB1, dot2bf(wA[m], cA1, 0.f));
            au[d] = cvt_pk_bf16(v0, v1);
          }
          A[m] = __builtin_bit_cast(s16x8, au);
        } else {
          A[m] = (s16x8){0, 0, 0, 0, 0, 0, 0, 0};
        }
      }
      const unsigned short* wb = wbtB + (((size_t)it) << 11) + (lane << 3);
      __builtin_amdgcn_s_setprio(1);
#pragma unroll
      for (int n = 0; n < 4; ++n) {
        s16x8 Bf = *(const s16x8*)(wb + (n << 9));
        acc[0][n] = __builtin_amdgcn_mfma_f32_16x16x32_bf16(A[0], Bf, acc[0][n], 0, 0, 0);
        acc[1][n] = __builtin_amdgcn_mfma_f32_16x16x32_bf16(A[1], Bf, acc[1][n], 0, 0, 0);
      }
      __builtin_amdgcn_s_setprio(0);
    }
  }

  // ===== epilogue: bias + store + per-channel stats (8-way replicated atomics) =====
  float sac[4], ssc[4];
#pragma unroll
  for (int n = 0; n < 4; ++n) { sac[n] = 0.f; ssc[n] = 0.f; }
#pragma unroll
  for (int m = 0; m < 2; ++m) {
    int px0 = (wv << 5) + (m << 4) + (s4 << 2);
#pragma unroll
    for (int n = 0; n < 4; ++n) {
      int oc = (n << 4) + l4;
      float bv = bias[oc];
      float4 o;
      o.x = acc[m][n][0] + bv;
      o.y = acc[m][n][1] + bv;
      o.z = acc[m][n][2] + bv;
      o.w = acc[m][n][3] + bv;
      sac[n] += o.x + o.y + o.z + o.w;
      ssc[n] += o.x * o.x + o.y * o.y + o.z * o.z + o.w * o.w;
      *(float4*)(y + (((size_t)(b << 6) + oc) << 14) + hw + px0) = o;
    }
  }
  // reduce over the 4 k-slice lanes (same l4, different s4): xor 16, 32
#pragma unroll
  for (int n = 0; n < 4; ++n) {
    sac[n] += __shfl_xor(sac[n], 16);
    sac[n] += __shfl_xor(sac[n], 32);
    ssc[n] += __shfl_xor(ssc[n], 16);
    ssc[n] += __shfl_xor(ssc[n], 32);
  }
  if (lane < 16) {
#pragma unroll
    for (int n = 0; n < 4; ++n) {
      int oc = (n << 4) + lane;
      offm[(wv << 6) + oc] = sac[n];
      offm[256 + (wv << 6) + oc] = ssc[n];
    }
  }
  __syncthreads();
  if (t < 64) {
    float S = offm[t] + offm[64 + t] + offm[128 + t] + offm[192 + t];
    float SS = offm[256 + t] + offm[320 + t] + offm[384 + t] + offm[448 + t];
    float* sb = stat + ((bx & 7) << 7);   // replica slot: contention 1024 -> 128 per address
    atomicAdd(sb + t, S);
    atomicAdd(sb + 64 + t, SS);
  }
}

// ---------------- kernel D: batchnorm scale/shift + relu, in place ----------------
__global__ __launch_bounds__(256) void bnrelu_kernel(
    float* __restrict__ y, const float* __restrict__ stat,
    const float* __restrict__ gamma, const float* __restrict__ beta) {
  __shared__ float gs[64], bs[64];
  int t = threadIdx.x;
  if (t < 64) {
    float S = 0.f, SS = 0.f;
#pragma unroll
    for (int k = 0; k < 8; ++k) {
      S += stat[(k << 7) + t];
      SS += stat[(k << 7) + 64 + t];
    }
    float mean = S * (1.f / (float)NPIX);
    float var = SS * (1.f / (float)NPIX) - mean * mean;
    float r = rsqrtf(var + EPSv);
    float g = gamma[t] * r;
    gs[t] = g;
    bs[t] = beta[t] - mean * g;
  }
  __syncthreads();
  float4* y4 = (float4*)y;
  for (int i = blockIdx.x * 256 + t; i < 2097152; i += gridDim.x * 256) {
    int c = (i >> 12) & 63;
    float g = gs[c];
    float bt = bs[c];
    float4 v = y4[i];
    v.x = fmaxf(v.x * g + bt, 0.f);
    v.y = fmaxf(v.y * g + bt, 0.f);
    v.z = fmaxf(v.z * g + bt, 0.f);
    v.w = fmaxf(v.w * g + bt, 0.f);
    y4[i] = v;
  }
}

extern "C" void kernel_launch(void* const* d_in, const int* in_sizes, int n_in,
                              void* d_out, int out_size, void* d_ws, size_t ws_size,
                              hipStream_t stream) {
  const float* x     = (const float*)d_in[0];
  const float* off_w = (const float*)d_in[1];
  const float* off_b = (const float*)d_in[2];
  const float* mod_w = (const float*)d_in[3];
  const float* mod_b = (const float*)d_in[4];
  const float* w     = (const float*)d_in[5];
  const float* b     = (const float*)d_in[6];
  const float* gamma = (const float*)d_in[7];
  const float* beta  = (const float*)d_in[8];
  float* out = (float*)d_out;
  float* ws  = (float*)d_ws;

  unsigned short* xt  = (unsigned short*)(ws + XT_OFF);
  unsigned short* wbtA = (unsigned short*)(ws + WBTA_OFF);
  unsigned short* wbtB = (unsigned short*)(ws + WBTB_OFF);
  float* stat  = ws + STAT_OFF;

  prep_xform_kernel<<<752, 256, 0, stream>>>(x, xt, off_w, mod_w, w, wbtA, wbtB, stat);
  fused_dconv_kernel<<<1024, 256, 0, stream>>>(xt, wbtA, wbtB, off_b, mod_b, b, out, stat);
  bnrelu_kernel<<<2048, 256, 0, stream>>>(out, stat, gamma, beta);
}

// Round 16
// 199.133 us; speedup vs baseline: 1.0179x; 1.0163x over previous
//
#include <hip/hip_runtime.h>
#include <math.h>

// Problem constants: B=8, C=64 (in), OC=64 (out), H=W=128, K=3x3=9, PAD=1.
#define Hn 128
#define Wn 128
#define HW 16384
#define NPIX 131072
#define EPSv 1e-5f

// ws layout (floats)
#define XT_OFF   0            // x_t bf16 channels-last [b][y][x][c]: 8388608 shorts = 4194304 floats
#define WBTA_OFF 4194304      // 20480 shorts = 10240 floats
#define WBTB_OFF 4204544      // 40960 shorts = 20480 floats
#define STAT_OFF 4225024      // 8 replicas x 128 (sum[64], sumsq[64]) = 1024 floats

// R26 (final form): revert R25's dot2 interp (regressed fused 102.7->107.5:
// VALUBusy 31->19% proved interp VALU was OVERLAPPED, not critical-path;
// dot2 lengthened the dep chain). This is R24's exact source = best-known
// configuration. Session ledger: 240.0 -> ~202 via operand-swap (R12),
// convA+deform fusion (R16), stats fusion + 8-way replicated atomics (R19),
// phase-1 LDS staging (R23). Phase-3 latency chain resisted 7 attacks
// (occupancy x2, MLP reorder, asm burst, LDS-gather [arithmetic], dot2,
// setprio[null]) -> accepted local optimum. Cooperative launch dead in
// harness (R20/R21). Fixed ~80us harness floor measured across 4 structure
// variants. Real-work budget: fused 103 + prep_xform 9 + bnrelu 11 (both
// at BW floor) + floor 80 = ~203us observed.

typedef short s16x8 __attribute__((ext_vector_type(8)));
typedef unsigned short u16x4 __attribute__((ext_vector_type(4)));
typedef float f32x4 __attribute__((ext_vector_type(4)));
typedef unsigned int u32x4 __attribute__((ext_vector_type(4)));

__device__ __forceinline__ unsigned short f2bf(float f) {
  unsigned u = __float_as_uint(f);
  return (unsigned short)((u + 0x7fffu + ((u >> 16) & 1u)) >> 16);  // RNE
}
__device__ __forceinline__ float bf2f(unsigned short s) {
  return __uint_as_float((unsigned)s << 16);
}
__device__ __forceinline__ unsigned cvt_pk_bf16(float lo, float hi) {
  unsigned r;
  asm("v_cvt_pk_bf16_f32 %0, %1, %2" : "=v"(r) : "v"(lo), "v"(hi));
  return r;
}

// ---------------- merged prep(+stat zero) + xform kernel ----------------
// blocks 0..511: xform x (NCHW fp32) -> x_t (NHWC bf16). blocks 512..751: weight pack.
__global__ __launch_bounds__(256) void prep_xform_kernel(
    const float* __restrict__ x, unsigned short* __restrict__ xt,
    const float* __restrict__ off_w, const float* __restrict__ mod_w,
    const float* __restrict__ w, unsigned short* __restrict__ wbtA,
    unsigned short* __restrict__ wbtB, float* __restrict__ stat) {
  int blk = blockIdx.x;
  if (blk < 512) {
    int b = blk & 7;
    int hw = ((blk >> 3) << 8) + threadIdx.x;   // 0..16383
    const float* xb = x + ((size_t)(b << 6) << 14) + hw;
    unsigned short* o = xt + (((size_t)(b << 14)) + hw) * 64;
#pragma unroll
    for (int g = 0; g < 8; ++g) {
      float v[8];
#pragma unroll
      for (int j = 0; j < 8; ++j) v[j] = xb[(size_t)((g << 3) + j) << 14];
      s16x8 pk;
#pragma unroll
      for (int j = 0; j < 8; ++j) pk[j] = (short)f2bf(v[j]);
      *(s16x8*)(o + (g << 3)) = pk;
    }
    return;
  }
  int i = ((blk - 512) << 8) + threadIdx.x;
  if (i < 1024) stat[i] = 0.f;   // 8 replica slots
  if (i < 20480) {
    // wbtA: A-operand (weights as rows) for phase 1 of the fused kernel.
    int e = i & 31, oc = (i >> 5) & 31, it = i >> 10;
    int tp = it % 5, chunk = it / 5;
    int tap = tp * 2 + (e >> 4);
    int c = (chunk << 4) + (e & 15);
    float v = 0.f;
    if (tap < 9) {
      if (oc < 18) v = off_w[(oc * 64 + c) * 9 + tap];
      else if (oc < 27) v = mod_w[((oc - 18) * 64 + c) * 9 + tap];
    }
    wbtA[i] = f2bf(v);
  } else if (i < 20480 + 40960) {
    // wbtB: B-operand fragments for phase 3 (deform).
    // index = ((it*4 + nt)*64 + lane)*8 + j
    // value = w[oc = nt*16 + (lane&15)][c][tap], where
    //   tap = (it%5)*2 + (lane>>5), c = (it/5)*16 + ((lane>>4)&1)*8 + j
    int j = i - 20480;
    int j3 = j & 7;
    int l = (j >> 3) & 63;
    int nt = (j >> 9) & 3;
    int it = j >> 11;
    int tp = it % 5, chunk = it / 5;
    int tap = tp * 2 + (l >> 5);
    int c = (chunk << 4) + (((l >> 4) & 1) << 3) + j3;
    int oc = (nt << 4) + (l & 15);
    float v = (tap < 9) ? w[(oc * 64 + c) * 9 + tap] : 0.f;
    wbtB[j] = f2bf(v);
  }
}

// ---------------- fused kernel: convA (async-staged ->LDS) + geometry + deform MFMA + stats ----------------
__global__ __launch_bounds__(256, 4) void fused_dconv_kernel(
    const unsigned short* __restrict__ xt, const unsigned short* __restrict__ wbtA,
    const unsigned short* __restrict__ wbtB,
    const float* __restrict__ off_b, const float* __restrict__ mod_b,
    const float* __restrict__ bias, float* __restrict__ y,
    float* __restrict__ stat) {
  __shared__ float offm[27 * 128];              // 13824 B; reused for stats reduce at the end
  // union: stage double-buffer (phase 1 only) aliases geow/geoi (phase 2+)
  __shared__ unsigned short un[2 * 3 * 128 * 16];  // 24576 B
  unsigned short* geow = un;                    // 9216 B: w00,w01,w10,w11 bf16 (mask folded)
  unsigned short* geoi = un + 4608;             // 2304 B: ibase = rbase*128+cbase
  int t = threadIdx.x;
  int bx = blockIdx.x;                  // 1024 = 8 b x 128 h
  int b = bx & 7, h = bx >> 3;
  int lane = t & 63, wv = t >> 6;
  int ln = lane & 15, quad = (lane >> 4) & 3;
  int hw = h << 7;

  const unsigned short* xtb = xt + ((size_t)(b << 14)) * 64;

  // ===== phase 1: offset+mask conv via MFMA (async global_load_lds staging, dbuf) =====
  {
    int p0 = (wv << 5) + ln, p1 = p0 + 16;
    int s_ = quad >> 1, cj = (quad & 1) << 3;
    int px_s = t >> 1, half_s = t & 1;   // staging lane mapping

    // STAGE(buf, chunk): issue 3-row async loads (row k OOB -> ds_write zeros)
    auto STAGE = [&](int buf, int chunk) {
#pragma unroll
      for (int k = 0; k < 3; ++k) {
        int gy = h - 1 + k;
        unsigned short* lp = un + buf * 6144 + (k << 11) + (wv << 9);  // wave-uniform base
        if ((unsigned)gy < 128u) {
          const unsigned short* gp =
              xtb + ((size_t)gy << 13) + (px_s << 6) + (chunk << 4) + (half_s << 3);
          __builtin_amdgcn_global_load_lds(
              (const __attribute__((address_space(1))) unsigned int*)gp,
              (__attribute__((address_space(3))) unsigned int*)lp, 16, 0, 0);
        } else {
          *(s16x8*)(un + buf * 6144 + (k << 11) + (t << 3)) = (s16x8){0, 0, 0, 0, 0, 0, 0, 0};
        }
      }
    };

    f32x4 acc1[2][2];
#pragma unroll
    for (int mt = 0; mt < 2; ++mt)
#pragma unroll
      for (int nt = 0; nt < 2; ++nt) acc1[mt][nt] = (f32x4){0.f, 0.f, 0.f, 0.f};

    STAGE(0, 0);
    __syncthreads();   // drain prologue loads

    for (int chunk = 0; chunk < 4; ++chunk) {
      if (chunk < 3) STAGE((chunk + 1) & 1, chunk + 1);  // async prefetch, flies under MFMAs
      const unsigned short* sb = un + (chunk & 1) * 6144;
#pragma unroll
      for (int tp = 0; tp < 5; ++tp) {
        int it = chunk * 5 + tp;
        int tap = tp * 2 + s_;
        s16x8 B0 = (s16x8){0, 0, 0, 0, 0, 0, 0, 0};
        s16x8 B1 = (s16x8){0, 0, 0, 0, 0, 0, 0, 0};
        if (tap < 9) {
          const unsigned short* rowl = sb + (tap / 3) * 2048 + cj;
          int gx0 = p0 + tap % 3 - 1;
          int gx1 = p1 + tap % 3 - 1;
          if (gx0 >= 0 && gx0 < Wn) B0 = *(const s16x8*)(rowl + (gx0 << 4));
          if (gx1 >= 0 && gx1 < Wn) B1 = *(const s16x8*)(rowl + (gx1 << 4));
        }
#pragma unroll
        for (int mt = 0; mt < 2; ++mt) {
          s16x8 A = *(const s16x8*)(wbtA + (size_t)((it << 5) + (mt << 4) + ln) * 32 + (quad << 3));
          acc1[mt][0] = __builtin_amdgcn_mfma_f32_16x16x32_bf16(A, B0, acc1[mt][0], 0, 0, 0);
          acc1[mt][1] = __builtin_amdgcn_mfma_f32_16x16x32_bf16(A, B1, acc1[mt][1], 0, 0, 0);
        }
      }
      __syncthreads();   // drains prefetch (mostly complete under MFMAs) + protects dbuf
    }

#pragma unroll
    for (int mt = 0; mt < 2; ++mt)
#pragma unroll
      for (int r = 0; r < 4; ++r) {
        int oc = (mt << 4) + (quad << 2) + r;
#pragma unroll
        for (int nt = 0; nt < 2; ++nt) {
          int px = (wv << 5) + (nt << 4) + ln;
          float val = acc1[mt][nt][r];
          if (oc < 18) {
            offm[(oc << 7) + px] = val + off_b[oc];
          } else if (oc < 27) {
            float z = val + mod_b[oc - 18];
            offm[(oc << 7) + px] = 2.f / (1.f + expf(-z));
          }
        }
      }
  }
  __syncthreads();   // offm ready; stage buffers dead from here -> geow/geoi may alias

  // ===== phase 2: geometry for 128 px x 9 taps from LDS =====
  for (int i = t; i < 1152; i += 256) {
    int tap = i >> 7, p2 = i & 127;
    float dy = offm[((2 * tap) << 7) + p2];
    float dx = offm[((2 * tap + 1) << 7) + p2];
    float m = offm[((18 + tap) << 7) + p2];
    float py = dy + (float)(h + tap / 3 - 1);
    float pxf = dx + (float)(p2 + tap % 3 - 1);
    float y0f = floorf(py), x0f = floorf(pxf);
    float ly = py - y0f, lx = pxf - x0f;
    int y0 = (int)y0f, x0 = (int)x0f;
    int y1 = y0 + 1, x1 = x0 + 1;
    float fy0 = (y0 >= 0 && y0 < Hn) ? 1.f : 0.f;
    float fy1 = (y1 >= 0 && y1 < Hn) ? 1.f : 0.f;
    float fx0 = (x0 >= 0 && x0 < Wn) ? 1.f : 0.f;
    float fx1 = (x1 >= 0 && x1 < Wn) ? 1.f : 0.f;
    float ax0 = (1.f - lx) * fx0, ax1 = lx * fx1;
    float ay0 = (1.f - ly) * fy0 * m, ay1 = ly * fy1 * m;
    int cy0 = min(max(y0, 0), Hn - 1), cy1 = min(max(y1, 0), Hn - 1);
    int cx0 = min(max(x0, 0), Wn - 1), cx1 = min(max(x1, 0), Wn - 1);
    int cbase = min(cx0, Wn - 2), rbase = min(cy0, Hn - 2);
    float gx0 = (cx0 == cbase ? ax0 : 0.f) + (cx1 == cbase ? ax1 : 0.f);
    float gx1 = (cx0 == cbase + 1 ? ax0 : 0.f) + (cx1 == cbase + 1 ? ax1 : 0.f);
    float gy0 = (cy0 == rbase ? ay0 : 0.f) + (cy1 == rbase ? ay1 : 0.f);
    float gy1 = (cy0 == rbase + 1 ? ay0 : 0.f) + (cy1 == rbase + 1 ? ay1 : 0.f);
    unsigned short* gw = geow + i * 4;
    gw[0] = f2bf(gy0 * gx0);
    gw[1] = f2bf(gy0 * gx1);
    gw[2] = f2bf(gy1 * gx0);
    gw[3] = f2bf(gy1 * gx1);
    geoi[i] = (unsigned short)((rbase << 7) + cbase);
  }
  __syncthreads();

  // ===== phase 3: deform MFMA (R16 structure) + setprio around MFMA cluster =====
  int l4 = ln;
  int s4 = lane >> 4;        // k-slice 0..3
  int tapS = lane >> 5;      // which tap of the pair
  int chalf = s4 & 1;        // which 8ch half of the 16ch chunk

  f32x4 acc[2][4];  // [m-tile (px 16)][n-tile (oc 16)]
#pragma unroll
  for (int m = 0; m < 2; ++m)
#pragma unroll
    for (int n = 0; n < 4; ++n) acc[m][n] = (f32x4){0.f, 0.f, 0.f, 0.f};

  for (int tp = 0; tp < 5; ++tp) {
    int tap = tp * 2 + tapS;
    bool live = (tap < 9);
    float w00[2], w01[2], w10[2], w11[2];
    const unsigned short* cpb[2];
#pragma unroll
    for (int m = 0; m < 2; ++m) {
      if (live) {
        int px = (wv << 5) + (m << 4) + l4;
        int gidx = (tap << 7) + px;
        u16x4 wq = *(const u16x4*)(geow + gidx * 4);
        unsigned ib = geoi[gidx];
        w00[m] = bf2f(wq[0]);
        w01[m] = bf2f(wq[1]);
        w10[m] = bf2f(wq[2]);
        w11[m] = bf2f(wq[3]);
        cpb[m] = xtb + (size_t)ib * 64 + (chalf << 3);
      } else {
        cpb[m] = xtb;
        w00[m] = w01[m] = w10[m] = w11[m] = 0.f;
      }
    }
#pragma unroll 2
    for (int chunk = 0; chunk < 4; ++chunk) {
      int it = chunk * 5 + tp;
      s16x8 A[2];
#pragma unroll
      for (int m = 0; m < 2; ++m) {
        if (live) {
          const unsigned short* cp = cpb[m] + (chunk << 4);
          s16x8 c00 = *(const s16x8*)(cp);
          s16x8 c01 = *(const s16x8*)(cp + 64);
          s16x8 c10 = *(const s16x8*)(cp + 8192);
          s16x8 c11 = *(const s16x8*)(cp + 8192 + 64);
          u32x4 au;
#pragma unroll
          for (int jj = 0; jj < 4; ++jj) {
            float v0 = w00[m] * bf2f((unsigned short)c00[2 * jj]) +
                       w01[m] * bf2f((unsigned short)c01[2 * jj]) +
                       w10[m] * bf2f((unsigned short)c10[2 * jj]) +
                       w11[m] * bf2f((unsigned short)c11[2 * jj]);
            float v1 = w00[m] * bf2f((unsigned short)c00[2 * jj + 1]) +
                       w01[m] * bf2f((unsigned short)c01[2 * jj + 1]) +
                       w10[m] * bf2f((unsigned short)c10[2 * jj + 1]) +
                       w11[m] * bf2f((unsigned short)c11[2 * jj + 1]);
            au[jj] = cvt_pk_bf16(v0, v1);
          }
          A[m] = __builtin_bit_cast(s16x8, au);
        } else {
          A[m] = (s16x8){0, 0, 0, 0, 0, 0, 0, 0};
        }
      }
      const unsigned short* wb = wbtB + (((size_t)it) << 11) + (lane << 3);
      __builtin_amdgcn_s_setprio(1);
#pragma unroll
      for (int n = 0; n < 4; ++n) {
        s16x8 Bf = *(const s16x8*)(wb + (n << 9));
        acc[0][n] = __builtin_amdgcn_mfma_f32_16x16x32_bf16(A[0], Bf, acc[0][n], 0, 0, 0);
        acc[1][n] = __builtin_amdgcn_mfma_f32_16x16x32_bf16(A[1], Bf, acc[1][n], 0, 0, 0);
      }
      __builtin_amdgcn_s_setprio(0);
    }
  }

  // ===== epilogue: bias + store + per-channel stats (8-way replicated atomics) =====
  float sac[4], ssc[4];
#pragma unroll
  for (int n = 0; n < 4; ++n) { sac[n] = 0.f; ssc[n] = 0.f; }
#pragma unroll
  for (int m = 0; m < 2; ++m) {
    int px0 = (wv << 5) + (m << 4) + (s4 << 2);
#pragma unroll
    for (int n = 0; n < 4; ++n) {
      int oc = (n << 4) + l4;
      float bv = bias[oc];
      float4 o;
      o.x = acc[m][n][0] + bv;
      o.y = acc[m][n][1] + bv;
      o.z = acc[m][n][2] + bv;
      o.w = acc[m][n][3] + bv;
      sac[n] += o.x + o.y + o.z + o.w;
      ssc[n] += o.x * o.x + o.y * o.y + o.z * o.z + o.w * o.w;
      *(float4*)(y + (((size_t)(b << 6) + oc) << 14) + hw + px0) = o;
    }
  }
  // reduce over the 4 k-slice lanes (same l4, different s4): xor 16, 32
#pragma unroll
  for (int n = 0; n < 4; ++n) {
    sac[n] += __shfl_xor(sac[n], 16);
    sac[n] += __shfl_xor(sac[n], 32);
    ssc[n] += __shfl_xor(ssc[n], 16);
    ssc[n] += __shfl_xor(ssc[n], 32);
  }
  if (lane < 16) {
#pragma unroll
    for (int n = 0; n < 4; ++n) {
      int oc = (n << 4) + lane;
      offm[(wv << 6) + oc] = sac[n];
      offm[256 + (wv << 6) + oc] = ssc[n];
    }
  }
  __syncthreads();
  if (t < 64) {
    float S = offm[t] + offm[64 + t] + offm[128 + t] + offm[192 + t];
    float SS = offm[256 + t] + offm[320 + t] + offm[384 + t] + offm[448 + t];
    float* sb = stat + ((bx & 7) << 7);   // replica slot: contention 1024 -> 128 per address
    atomicAdd(sb + t, S);
    atomicAdd(sb + 64 + t, SS);
  }
}

// ---------------- kernel D: batchnorm scale/shift + relu, in place ----------------
__global__ __launch_bounds__(256) void bnrelu_kernel(
    float* __restrict__ y, const float* __restrict__ stat,
    const float* __restrict__ gamma, const float* __restrict__ beta) {
  __shared__ float gs[64], bs[64];
  int t = threadIdx.x;
  if (t < 64) {
    float S = 0.f, SS = 0.f;
#pragma unroll
    for (int k = 0; k < 8; ++k) {
      S += stat[(k << 7) + t];
      SS += stat[(k << 7) + 64 + t];
    }
    float mean = S * (1.f / (float)NPIX);
    float var = SS * (1.f / (float)NPIX) - mean * mean;
    float r = rsqrtf(var + EPSv);
    float g = gamma[t] * r;
    gs[t] = g;
    bs[t] = beta[t] - mean * g;
  }
  __syncthreads();
  float4* y4 = (float4*)y;
  for (int i = blockIdx.x * 256 + t; i < 2097152; i += gridDim.x * 256) {
    int c = (i >> 12) & 63;
    float g = gs[c];
    float bt = bs[c];
    float4 v = y4[i];
    v.x = fmaxf(v.x * g + bt, 0.f);
    v.y = fmaxf(v.y * g + bt, 0.f);
    v.z = fmaxf(v.z * g + bt, 0.f);
    v.w = fmaxf(v.w * g + bt, 0.f);
    y4[i] = v;
  }
}

extern "C" void kernel_launch(void* const* d_in, const int* in_sizes, int n_in,
                              void* d_out, int out_size, void* d_ws, size_t ws_size,
                              hipStream_t stream) {
  const float* x     = (const float*)d_in[0];
  const float* off_w = (const float*)d_in[1];
  const float* off_b = (const float*)d_in[2];
  const float* mod_w = (const float*)d_in[3];
  const float* mod_b = (const float*)d_in[4];
  const float* w     = (const float*)d_in[5];
  const float* b     = (const float*)d_in[6];
  const float* gamma = (const float*)d_in[7];
  const float* beta  = (const float*)d_in[8];
  float* out = (float*)d_out;
  float* ws  = (float*)d_ws;

  unsigned short* xt  = (unsigned short*)(ws + XT_OFF);
  unsigned short* wbtA = (unsigned short*)(ws + WBTA_OFF);
  unsigned short* wbtB = (unsigned short*)(ws + WBTB_OFF);
  float* stat  = ws + STAT_OFF;

  prep_xform_kernel<<<752, 256, 0, stream>>>(x, xt, off_w, mod_w, w, wbtA, wbtB, stat);
  fused_dconv_kernel<<<1024, 256, 0, stream>>>(xt, wbtA, wbtB, off_b, mod_b, b, out, stat);
  bnrelu_kernel<<<2048, 256, 0, stream>>>(out, stat, gamma, beta);
}